// Round 5
// baseline (216.233 us; speedup 1.0000x reference)
//
#include <hip/hip_runtime.h>
#include <hip/hip_bf16.h>

typedef __attribute__((ext_vector_type(8))) short short8;
typedef __attribute__((ext_vector_type(4))) float floatx4;
typedef unsigned short ushort_t;
typedef unsigned int uint_t;

#define DOUT   256
#define KPAD   864          // 320 + 320 + 224 (segments padded to x32)
#define XPITCH 872          // ushorts per LDS row (436 dwords; 218 uint2)
#define TB     16           // tokens per block; 256 threads -> 16 thr/token (verified path)
#define NTOK   16384        // 32*512
#define NPREP_T 27          // fragment-transpose blocks (864/32 k-slabs)

static __device__ inline uint_t pack2bf(float x, float y) {
    __hip_bfloat162 h = __float22bfloat162_rn(make_float2(x, y));
    return *(uint_t*)&h;
}
static __device__ inline ushort_t f2bf(float f) {
    union { float f; uint_t u; } a; a.f = f;
    uint_t u = a.u;
    return (ushort_t)((u + 0x7FFFu + ((u >> 16) & 1u)) >> 16);
}
static __device__ inline float dot4(float4 a, float4 b) {
    return a.x * b.x + a.y * b.y + a.z * b.z + a.w * b.w;
}

// ---------------------------------------------------------------------------
// Merged prep (28 blocks) — VERIFIED PASSING in round 3. Unchanged.
// ---------------------------------------------------------------------------
__global__ __launch_bounds__(256) void k_prep(
    const float* __restrict__ W0, const float* __restrict__ W1,
    const float* __restrict__ W2,
    const float* __restrict__ b0, const float* __restrict__ b1,
    const float* __restrict__ b2,
    const float* __restrict__ Wa, const float* __restrict__ ba,
    float* __restrict__ u, float* __restrict__ lb, ushort_t* __restrict__ Wtf)
{
    __shared__ ushort_t tile[32][258];   // k-row x n-col, +2 pad
    int tid = threadIdx.x;
    int lane = tid & 63;
    int w = tid >> 6;                    // wave 0..3
    if (blockIdx.x < NPREP_T) {
        int kc = blockIdx.x;
        float4 wa4 = ((const float4*)Wa)[lane];     // cols 4*lane..4*lane+3
        float part[8];
        #pragma unroll
        for (int j = 0; j < 8; ++j) {
            int kk = w + 4 * j;                     // row within slab
            int kp = kc * 32 + kk;
            float4 v = make_float4(0.f, 0.f, 0.f, 0.f);
            const float* src = nullptr;
            if (kp < 320)      { if (kp < 300) src = W0 + kp * DOUT; }
            else if (kp < 640) { int o = kp - 320; if (o < 300) src = W1 + o * DOUT; }
            else               { int o = kp - 640; if (o < 200) src = W2 + o * DOUT; }
            if (src) v = *(const float4*)(src + 4 * lane);
            tile[kk][4 * lane + 0] = f2bf(v.x);
            tile[kk][4 * lane + 1] = f2bf(v.y);
            tile[kk][4 * lane + 2] = f2bf(v.z);
            tile[kk][4 * lane + 3] = f2bf(v.w);
            part[j] = dot4(v, wa4);
        }
        // u[k] = full-wave reduction of fp32 partials (each row lives in one wave)
        #pragma unroll
        for (int j = 0; j < 8; ++j) {
            float p = part[j];
            #pragma unroll
            for (int m = 1; m < 64; m <<= 1) p += __shfl_xor(p, m);
            if (lane == 0) u[kc * 32 + w + 4 * j] = p;
        }
        __syncthreads();
        int kq = (lane >> 4) * 8;
        int nc = lane & 15;
        #pragma unroll
        for (int i = 0; i < 4; ++i) {
            int nt = w * 4 + i;
            union { uint4 v; ushort_t s[8]; } pk;
            #pragma unroll
            for (int j = 0; j < 8; ++j) pk.s[j] = tile[kq + j][nt * 16 + nc];
            *(uint4*)(Wtf + ((size_t)(nt * 27 + kc) * 64 + lane) * 8) = pk.v;
        }
    } else {
        // tail: lb via waves 0..2; zero the u pad read by seg2 logit loads
        if (w < 3) {
            const float* bn = (w == 0) ? b0 : ((w == 1) ? b1 : b2);
            float acc = 0.f;
            #pragma unroll
            for (int j = 0; j < 4; ++j) {
                int c = lane + 64 * j;
                acc += bn[c] * Wa[c];
            }
            #pragma unroll
            for (int m = 1; m < 64; m <<= 1) acc += __shfl_xor(acc, m);
            if (lane == 0) lb[w] = acc + ba[0];
        }
        if (tid < 32) u[864 + tid] = 0.f;
    }
}

// ---------------------------------------------------------------------------
// Main: gather -> logits/softmax -> alpha-scaled bf16 pack -> MFMA GEMM.
// Block: 256 threads (4 waves), 16 tokens, 16 threads/token; grid 1024.
// Pre-barrier section is BYTE-IDENTICAL to the round-3-verified kernel
// (same g[14] gather, masks, 16-lane butterfly, pack indices) — only the
// token-row count (trow in [0,16)) and the post-barrier MFMA fan-out change:
// 4 waves x 4 N-tiles/wave (was 8 waves x 2), single M-tile.
// LDS 28.2 KB -> up to 5 blocks/CU (20 waves) vs 2 blocks (16 waves) before.
// ---------------------------------------------------------------------------
__global__ __launch_bounds__(256, 4) void k_main(
    const int* __restrict__ ids,
    const float* __restrict__ E0, const float* __restrict__ E1,
    const float* __restrict__ E2,
    const float* __restrict__ b0, const float* __restrict__ b1,
    const float* __restrict__ b2,
    const float* __restrict__ u, const float* __restrict__ lb,
    const ushort_t* __restrict__ Wtf,
    float* __restrict__ out)
{
    __shared__ __align__(16) ushort_t Xs[TB][XPITCH];   // 27904 B
    __shared__ float alphaS[TB][4];

    int tid = threadIdx.x;
    int tok0 = blockIdx.x * TB;

    // ---- batched gather: 16 threads/token; all 14 float4 loads pinned first ----
    int trow = tid >> 4, sub = tid & 15;
    int id = ids[tok0 + trow];
    uint2* Xd2 = (uint2*)&Xs[trow][0];
    const float4* p0 = (const float4*)E0 + (size_t)id * 75;
    const float4* p1 = (const float4*)E1 + (size_t)id * 75;
    const float4* p2 = (const float4*)E2 + (size_t)id * 50;
    float4 f4z = make_float4(0.f, 0.f, 0.f, 0.f);

    float4 g[14];
    g[0] = p0[sub];      g[1] = p0[sub + 16];
    g[2] = p0[sub + 32]; g[3] = p0[sub + 48];
    g[4] = (sub < 11) ? p0[sub + 64] : f4z;
    g[5] = p1[sub];      g[6] = p1[sub + 16];
    g[7] = p1[sub + 32]; g[8] = p1[sub + 48];
    g[9] = (sub < 11) ? p1[sub + 64] : f4z;
    g[10] = p2[sub];      g[11] = p2[sub + 16];
    g[12] = p2[sub + 32];
    g[13] = (sub < 2) ? p2[sub + 48] : f4z;
    __builtin_amdgcn_sched_barrier(0);   // keep all 14 loads issued before consume

    // ---- fp32 logit partials ----
    float l0 = 0.f, l1 = 0.f, l2 = 0.f;
    #pragma unroll
    for (int j = 0; j < 5; ++j) {
        float4 t = g[j], uu = *(const float4*)(u + 4 * (sub + 16 * j));
        l0 += t.x * uu.x + t.y * uu.y + t.z * uu.z + t.w * uu.w;
    }
    #pragma unroll
    for (int j = 0; j < 5; ++j) {
        float4 t = g[5 + j], uu = *(const float4*)(u + 320 + 4 * (sub + 16 * j));
        l1 += t.x * uu.x + t.y * uu.y + t.z * uu.z + t.w * uu.w;
    }
    #pragma unroll
    for (int j = 0; j < 4; ++j) {
        float4 t = g[10 + j], uu = *(const float4*)(u + 640 + 4 * (sub + 16 * j));
        l2 += t.x * uu.x + t.y * uu.y + t.z * uu.z + t.w * uu.w;
    }
    // butterfly over the token's 16 lanes -> every lane has the full sums
    #pragma unroll
    for (int m = 1; m < 16; m <<= 1) {
        l0 += __shfl_xor(l0, m);
        l1 += __shfl_xor(l1, m);
        l2 += __shfl_xor(l2, m);
    }
    l0 += lb[0]; l1 += lb[1]; l2 += lb[2];
    float mx = fmaxf(l0, fmaxf(l1, l2));
    float e0 = __expf(l0 - mx), e1 = __expf(l1 - mx), e2 = __expf(l2 - mx);
    float inv = 1.f / (e0 + e1 + e2);
    float a0 = e0 * inv, a1 = e1 * inv, a2 = e2 * inv;
    if (sub == 0) { alphaS[trow][0] = a0; alphaS[trow][1] = a1; alphaS[trow][2] = a2; }

    // ---- pack alpha-scaled bf16 into LDS (all writes within row pitch 218) ----
    #pragma unroll
    for (int j = 0; j < 5; ++j) {
        float4 t = g[j];
        Xd2[sub + 16 * j] = make_uint2(pack2bf(a0 * t.x, a0 * t.y), pack2bf(a0 * t.z, a0 * t.w));
    }
    #pragma unroll
    for (int j = 0; j < 5; ++j) {
        float4 t = g[5 + j];
        Xd2[80 + sub + 16 * j] = make_uint2(pack2bf(a1 * t.x, a1 * t.y), pack2bf(a1 * t.z, a1 * t.w));
    }
    #pragma unroll
    for (int j = 0; j < 3; ++j) {
        float4 t = g[10 + j];
        Xd2[160 + sub + 16 * j] = make_uint2(pack2bf(a2 * t.x, a2 * t.y), pack2bf(a2 * t.z, a2 * t.w));
    }
    if (sub < 2) {   // seg2 tail: only granules 48,49 are real data
        float4 t = g[13];
        Xd2[160 + 48 + sub] = make_uint2(pack2bf(a2 * t.x, a2 * t.y), pack2bf(a2 * t.z, a2 * t.w));
    }
    uint2 z2 = make_uint2(0u, 0u);
    for (int i = 75 + sub;  i < 80;  i += 16) Xd2[i] = z2;   // seg0 pad
    for (int i = 155 + sub; i < 160; i += 16) Xd2[i] = z2;   // seg1 pad
    for (int i = 210 + sub; i < 218; i += 16) Xd2[i] = z2;   // seg2 pad + row pad
    __syncthreads();

    // ---- MFMA GEMM: wave w (0..3) owns N-tiles {4w..4w+3}; single M-tile ----
    int lane = tid & 63;
    int w = tid >> 6;               // 0..3
    int mrow = lane & 15;
    int kg8 = (lane >> 4) * 8;

    const ushort_t* bq0 = Wtf + ((size_t)((4 * w + 0) * 27) * 64 + lane) * 8;
    const ushort_t* bq1 = Wtf + ((size_t)((4 * w + 1) * 27) * 64 + lane) * 8;
    const ushort_t* bq2 = Wtf + ((size_t)((4 * w + 2) * 27) * 64 + lane) * 8;
    const ushort_t* bq3 = Wtf + ((size_t)((4 * w + 3) * 27) * 64 + lane) * 8;

    floatx4 acc0 = {0.f, 0.f, 0.f, 0.f};
    floatx4 acc1 = {0.f, 0.f, 0.f, 0.f};
    floatx4 acc2 = {0.f, 0.f, 0.f, 0.f};
    floatx4 acc3 = {0.f, 0.f, 0.f, 0.f};

    #pragma unroll
    for (int kc = 0; kc < 27; ++kc) {
        short8 av  = *(const short8*)&Xs[mrow][kc * 32 + kg8];
        short8 bv0 = *(const short8*)(bq0 + kc * 512);
        short8 bv1 = *(const short8*)(bq1 + kc * 512);
        short8 bv2 = *(const short8*)(bq2 + kc * 512);
        short8 bv3 = *(const short8*)(bq3 + kc * 512);
        acc0 = __builtin_amdgcn_mfma_f32_16x16x32_bf16(av, bv0, acc0, 0, 0, 0);
        acc1 = __builtin_amdgcn_mfma_f32_16x16x32_bf16(av, bv1, acc1, 0, 0, 0);
        acc2 = __builtin_amdgcn_mfma_f32_16x16x32_bf16(av, bv2, acc2, 0, 0, 0);
        acc3 = __builtin_amdgcn_mfma_f32_16x16x32_bf16(av, bv3, acc3, 0, 0, 0);
    }

    // ---- epilogue: out = acc + a0*b0 + a1*b1 + a2*b2 (fp32) ----
    float bb0[4], bb1[4], bb2[4];
    #pragma unroll
    for (int nt = 0; nt < 4; ++nt) {
        int n = (4 * w + nt) * 16 + mrow;
        bb0[nt] = b0[n]; bb1[nt] = b1[n]; bb2[nt] = b2[n];
    }
    #pragma unroll
    for (int r = 0; r < 4; ++r) {
        int tok = (lane >> 4) * 4 + r;
        float t0 = alphaS[tok][0], t1 = alphaS[tok][1], t2 = alphaS[tok][2];
        size_t rowoff = (size_t)(tok0 + tok) * DOUT;
        out[rowoff + (4 * w + 0) * 16 + mrow] = acc0[r] + t0 * bb0[0] + t1 * bb1[0] + t2 * bb2[0];
        out[rowoff + (4 * w + 1) * 16 + mrow] = acc1[r] + t0 * bb0[1] + t1 * bb1[1] + t2 * bb2[1];
        out[rowoff + (4 * w + 2) * 16 + mrow] = acc2[r] + t0 * bb0[2] + t1 * bb1[2] + t2 * bb2[2];
        out[rowoff + (4 * w + 3) * 16 + mrow] = acc3[r] + t0 * bb0[3] + t1 * bb1[3] + t2 * bb2[3];
    }
}

extern "C" void kernel_launch(void* const* d_in, const int* in_sizes, int n_in,
                              void* d_out, int out_size, void* d_ws, size_t ws_size,
                              hipStream_t stream) {
    const int*   ids = (const int*)d_in[0];
    const float* E0  = (const float*)d_in[1];
    const float* E1  = (const float*)d_in[2];
    const float* E2  = (const float*)d_in[3];
    const float* W0  = (const float*)d_in[4];
    const float* b0  = (const float*)d_in[5];
    const float* W1  = (const float*)d_in[6];
    const float* b1  = (const float*)d_in[7];
    const float* W2  = (const float*)d_in[8];
    const float* b2  = (const float*)d_in[9];
    const float* Wa  = (const float*)d_in[10];
    const float* ba  = (const float*)d_in[11];

    float* u      = (float*)d_ws;                       // 896 floats (zero-padded)
    float* lb     = u + 896;                            // 3 floats
    ushort_t* Wtf = (ushort_t*)((char*)d_ws + 4096);    // 432 KB fragment-ordered B

    k_prep<<<NPREP_T + 1, 256, 0, stream>>>(W0, W1, W2, b0, b1, b2, Wa, ba,
                                            u, lb, Wtf);
    k_main<<<NTOK / TB, 256, 0, stream>>>(ids, E0, E1, E2, b0, b1, b2, u, lb, Wtf,
                                          (float*)d_out);
}

// Round 6
// 181.915 us; speedup vs baseline: 1.1886x; 1.1886x over previous
//
#include <hip/hip_runtime.h>
#include <hip/hip_bf16.h>

typedef __attribute__((ext_vector_type(8))) short short8;
typedef __attribute__((ext_vector_type(4))) float floatx4;
typedef unsigned short ushort_t;
typedef unsigned int uint_t;

#define DOUT   256
#define KPAD   864          // 320 + 320 + 224 (segments padded to x32)
#define XPITCH 872          // ushorts per LDS row (436 dwords; 218 uint2)
#define TB     32           // tokens per block (verified structure)
#define NTOK   16384        // 32*512
#define NPREP_T 27          // fragment-transpose blocks (864/32 k-slabs)

static __device__ inline uint_t pack2bf(float x, float y) {
    __hip_bfloat162 h = __float22bfloat162_rn(make_float2(x, y));
    return *(uint_t*)&h;
}
static __device__ inline ushort_t f2bf(float f) {
    union { float f; uint_t u; } a; a.f = f;
    uint_t u = a.u;
    return (ushort_t)((u + 0x7FFFu + ((u >> 16) & 1u)) >> 16);
}
static __device__ inline float dot4(float4 a, float4 b) {
    return a.x * b.x + a.y * b.y + a.z * b.z + a.w * b.w;
}
// Non-temporal float4 load (nt flag: no-allocate/evict-first). Embedding rows
// have ~zero reuse within a dispatch — L1 allocation only throttles the gather.
static __device__ inline float4 ldnt(const float4* p) {
    floatx4 v = __builtin_nontemporal_load((const floatx4*)p);
    return make_float4(v.x, v.y, v.z, v.w);
}

// ---------------------------------------------------------------------------
// Merged prep (28 blocks) — VERIFIED PASSING in round 3. Unchanged.
// ---------------------------------------------------------------------------
__global__ __launch_bounds__(256) void k_prep(
    const float* __restrict__ W0, const float* __restrict__ W1,
    const float* __restrict__ W2,
    const float* __restrict__ b0, const float* __restrict__ b1,
    const float* __restrict__ b2,
    const float* __restrict__ Wa, const float* __restrict__ ba,
    float* __restrict__ u, float* __restrict__ lb, ushort_t* __restrict__ Wtf)
{
    __shared__ ushort_t tile[32][258];   // k-row x n-col, +2 pad
    int tid = threadIdx.x;
    int lane = tid & 63;
    int w = tid >> 6;                    // wave 0..3
    if (blockIdx.x < NPREP_T) {
        int kc = blockIdx.x;
        float4 wa4 = ((const float4*)Wa)[lane];     // cols 4*lane..4*lane+3
        float part[8];
        #pragma unroll
        for (int j = 0; j < 8; ++j) {
            int kk = w + 4 * j;                     // row within slab
            int kp = kc * 32 + kk;
            float4 v = make_float4(0.f, 0.f, 0.f, 0.f);
            const float* src = nullptr;
            if (kp < 320)      { if (kp < 300) src = W0 + kp * DOUT; }
            else if (kp < 640) { int o = kp - 320; if (o < 300) src = W1 + o * DOUT; }
            else               { int o = kp - 640; if (o < 200) src = W2 + o * DOUT; }
            if (src) v = *(const float4*)(src + 4 * lane);
            tile[kk][4 * lane + 0] = f2bf(v.x);
            tile[kk][4 * lane + 1] = f2bf(v.y);
            tile[kk][4 * lane + 2] = f2bf(v.z);
            tile[kk][4 * lane + 3] = f2bf(v.w);
            part[j] = dot4(v, wa4);
        }
        // u[k] = full-wave reduction of fp32 partials (each row lives in one wave)
        #pragma unroll
        for (int j = 0; j < 8; ++j) {
            float p = part[j];
            #pragma unroll
            for (int m = 1; m < 64; m <<= 1) p += __shfl_xor(p, m);
            if (lane == 0) u[kc * 32 + w + 4 * j] = p;
        }
        __syncthreads();
        int kq = (lane >> 4) * 8;
        int nc = lane & 15;
        #pragma unroll
        for (int i = 0; i < 4; ++i) {
            int nt = w * 4 + i;
            union { uint4 v; ushort_t s[8]; } pk;
            #pragma unroll
            for (int j = 0; j < 8; ++j) pk.s[j] = tile[kq + j][nt * 16 + nc];
            *(uint4*)(Wtf + ((size_t)(nt * 27 + kc) * 64 + lane) * 8) = pk.v;
        }
    } else {
        // tail: lb via waves 0..2; zero the u pad read by seg2 logit loads
        if (w < 3) {
            const float* bn = (w == 0) ? b0 : ((w == 1) ? b1 : b2);
            float acc = 0.f;
            #pragma unroll
            for (int j = 0; j < 4; ++j) {
                int c = lane + 64 * j;
                acc += bn[c] * Wa[c];
            }
            #pragma unroll
            for (int m = 1; m < 64; m <<= 1) acc += __shfl_xor(acc, m);
            if (lane == 0) lb[w] = acc + ba[0];
        }
        if (tid < 32) u[864 + tid] = 0.f;
    }
}

// ---------------------------------------------------------------------------
// Main: batched gather -> logits/softmax -> alpha-scaled bf16 pack -> single-acc
//       MFMA GEMM with fragment-streamed B -> epilogue (+ alpha-weighted bias).
// Block: 512 threads (8 waves), 32 tokens; grid 512.
// Identical to the round-3 verified kernel EXCEPT: the 14 gather loads use
// the nt (non-temporal) cache policy to stop L1 allocation throttling the
// random-gather miss concurrency.
// ---------------------------------------------------------------------------
__global__ __launch_bounds__(512, 4) void k_main(
    const int* __restrict__ ids,
    const float* __restrict__ E0, const float* __restrict__ E1,
    const float* __restrict__ E2,
    const float* __restrict__ b0, const float* __restrict__ b1,
    const float* __restrict__ b2,
    const float* __restrict__ u, const float* __restrict__ lb,
    const ushort_t* __restrict__ Wtf,
    float* __restrict__ out)
{
    __shared__ __align__(16) ushort_t Xs[TB][XPITCH];   // 55808 B (alpha-scaled bf16)
    __shared__ float alphaS[TB][4];

    int tid = threadIdx.x;
    int tok0 = blockIdx.x * TB;

    // ---- batched gather: 16 threads/token; all 14 float4 loads pinned first ----
    int trow = tid >> 4, sub = tid & 15;
    int id = ids[tok0 + trow];
    uint2* Xd2 = (uint2*)&Xs[trow][0];
    const float4* p0 = (const float4*)E0 + (size_t)id * 75;
    const float4* p1 = (const float4*)E1 + (size_t)id * 75;
    const float4* p2 = (const float4*)E2 + (size_t)id * 50;
    float4 f4z = make_float4(0.f, 0.f, 0.f, 0.f);

    float4 g[14];
    g[0] = ldnt(p0 + sub);      g[1] = ldnt(p0 + sub + 16);
    g[2] = ldnt(p0 + sub + 32); g[3] = ldnt(p0 + sub + 48);
    g[4] = (sub < 11) ? ldnt(p0 + sub + 64) : f4z;
    g[5] = ldnt(p1 + sub);      g[6] = ldnt(p1 + sub + 16);
    g[7] = ldnt(p1 + sub + 32); g[8] = ldnt(p1 + sub + 48);
    g[9] = (sub < 11) ? ldnt(p1 + sub + 64) : f4z;
    g[10] = ldnt(p2 + sub);      g[11] = ldnt(p2 + sub + 16);
    g[12] = ldnt(p2 + sub + 32);
    g[13] = (sub < 2) ? ldnt(p2 + sub + 48) : f4z;
    __builtin_amdgcn_sched_barrier(0);   // keep all 14 loads issued before consume

    // ---- fp32 logit partials ----
    float l0 = 0.f, l1 = 0.f, l2 = 0.f;
    #pragma unroll
    for (int j = 0; j < 5; ++j) {
        float4 t = g[j], uu = *(const float4*)(u + 4 * (sub + 16 * j));
        l0 += t.x * uu.x + t.y * uu.y + t.z * uu.z + t.w * uu.w;
    }
    #pragma unroll
    for (int j = 0; j < 5; ++j) {
        float4 t = g[5 + j], uu = *(const float4*)(u + 320 + 4 * (sub + 16 * j));
        l1 += t.x * uu.x + t.y * uu.y + t.z * uu.z + t.w * uu.w;
    }
    #pragma unroll
    for (int j = 0; j < 4; ++j) {
        float4 t = g[10 + j], uu = *(const float4*)(u + 640 + 4 * (sub + 16 * j));
        l2 += t.x * uu.x + t.y * uu.y + t.z * uu.z + t.w * uu.w;
    }
    // butterfly over the token's 16 lanes -> every lane has the full sums
    #pragma unroll
    for (int m = 1; m < 16; m <<= 1) {
        l0 += __shfl_xor(l0, m);
        l1 += __shfl_xor(l1, m);
        l2 += __shfl_xor(l2, m);
    }
    l0 += lb[0]; l1 += lb[1]; l2 += lb[2];
    float mx = fmaxf(l0, fmaxf(l1, l2));
    float e0 = __expf(l0 - mx), e1 = __expf(l1 - mx), e2 = __expf(l2 - mx);
    float inv = 1.f / (e0 + e1 + e2);
    float a0 = e0 * inv, a1 = e1 * inv, a2 = e2 * inv;
    if (sub == 0) { alphaS[trow][0] = a0; alphaS[trow][1] = a1; alphaS[trow][2] = a2; }

    // ---- pack alpha-scaled bf16 into LDS (all writes within row pitch 218) ----
    #pragma unroll
    for (int j = 0; j < 5; ++j) {
        float4 t = g[j];
        Xd2[sub + 16 * j] = make_uint2(pack2bf(a0 * t.x, a0 * t.y), pack2bf(a0 * t.z, a0 * t.w));
    }
    #pragma unroll
    for (int j = 0; j < 5; ++j) {
        float4 t = g[5 + j];
        Xd2[80 + sub + 16 * j] = make_uint2(pack2bf(a1 * t.x, a1 * t.y), pack2bf(a1 * t.z, a1 * t.w));
    }
    #pragma unroll
    for (int j = 0; j < 3; ++j) {
        float4 t = g[10 + j];
        Xd2[160 + sub + 16 * j] = make_uint2(pack2bf(a2 * t.x, a2 * t.y), pack2bf(a2 * t.z, a2 * t.w));
    }
    if (sub < 2) {   // seg2 tail: only granules 48,49 are real data
        float4 t = g[13];
        Xd2[160 + 48 + sub] = make_uint2(pack2bf(a2 * t.x, a2 * t.y), pack2bf(a2 * t.z, a2 * t.w));
    }
    uint2 z2 = make_uint2(0u, 0u);
    for (int i = 75 + sub;  i < 80;  i += 16) Xd2[i] = z2;   // seg0 pad
    for (int i = 155 + sub; i < 160; i += 16) Xd2[i] = z2;   // seg1 pad
    for (int i = 210 + sub; i < 218; i += 16) Xd2[i] = z2;   // seg2 pad + row pad
    __syncthreads();

    // ---- MFMA GEMM: wave w owns N-tiles {2w, 2w+1}; single acc set ----
    int lane = tid & 63;
    int w = tid >> 6;               // 0..7
    int mrow = lane & 15;
    int kg8 = (lane >> 4) * 8;

    const ushort_t* bq0 = Wtf + ((size_t)((2 * w + 0) * 27) * 64 + lane) * 8;
    const ushort_t* bq1 = Wtf + ((size_t)((2 * w + 1) * 27) * 64 + lane) * 8;

    floatx4 acc[2][2];
    {
        floatx4 z = {0.f, 0.f, 0.f, 0.f};
        acc[0][0] = z; acc[0][1] = z; acc[1][0] = z; acc[1][1] = z;
    }

    #pragma unroll
    for (int kc = 0; kc < 27; ++kc) {
        short8 av0 = *(const short8*)&Xs[mrow][kc * 32 + kg8];
        short8 av1 = *(const short8*)&Xs[16 + mrow][kc * 32 + kg8];
        short8 bv0 = *(const short8*)(bq0 + kc * 512);
        short8 bv1 = *(const short8*)(bq1 + kc * 512);
        acc[0][0] = __builtin_amdgcn_mfma_f32_16x16x32_bf16(av0, bv0, acc[0][0], 0, 0, 0);
        acc[1][0] = __builtin_amdgcn_mfma_f32_16x16x32_bf16(av1, bv0, acc[1][0], 0, 0, 0);
        acc[0][1] = __builtin_amdgcn_mfma_f32_16x16x32_bf16(av0, bv1, acc[0][1], 0, 0, 0);
        acc[1][1] = __builtin_amdgcn_mfma_f32_16x16x32_bf16(av1, bv1, acc[1][1], 0, 0, 0);
    }

    // ---- epilogue: out = acc + a0*b0 + a1*b1 + a2*b2 (fp32) ----
    float bb0[2], bb1[2], bb2[2];
    #pragma unroll
    for (int nt = 0; nt < 2; ++nt) {
        int n = (2 * w + nt) * 16 + mrow;
        bb0[nt] = b0[n]; bb1[nt] = b1[n]; bb2[nt] = b2[n];
    }
    #pragma unroll
    for (int mt = 0; mt < 2; ++mt) {
        #pragma unroll
        for (int r = 0; r < 4; ++r) {
            int tok = mt * 16 + (lane >> 4) * 4 + r;
            float t0 = alphaS[tok][0], t1 = alphaS[tok][1], t2 = alphaS[tok][2];
            size_t rowoff = (size_t)(tok0 + tok) * DOUT;
            #pragma unroll
            for (int nt = 0; nt < 2; ++nt) {
                int n = (2 * w + nt) * 16 + mrow;
                out[rowoff + n] = acc[mt][nt][r] + t0 * bb0[nt] + t1 * bb1[nt] + t2 * bb2[nt];
            }
        }
    }
}

extern "C" void kernel_launch(void* const* d_in, const int* in_sizes, int n_in,
                              void* d_out, int out_size, void* d_ws, size_t ws_size,
                              hipStream_t stream) {
    const int*   ids = (const int*)d_in[0];
    const float* E0  = (const float*)d_in[1];
    const float* E1  = (const float*)d_in[2];
    const float* E2  = (const float*)d_in[3];
    const float* W0  = (const float*)d_in[4];
    const float* b0  = (const float*)d_in[5];
    const float* W1  = (const float*)d_in[6];
    const float* b1  = (const float*)d_in[7];
    const float* W2  = (const float*)d_in[8];
    const float* b2  = (const float*)d_in[9];
    const float* Wa  = (const float*)d_in[10];
    const float* ba  = (const float*)d_in[11];

    float* u      = (float*)d_ws;                       // 896 floats (zero-padded)
    float* lb     = u + 896;                            // 3 floats
    ushort_t* Wtf = (ushort_t*)((char*)d_ws + 4096);    // 432 KB fragment-ordered B

    k_prep<<<NPREP_T + 1, 256, 0, stream>>>(W0, W1, W2, b0, b1, b2, Wa, ba,
                                            u, lb, Wtf);
    k_main<<<NTOK / TB, 512, 0, stream>>>(ids, E0, E1, E2, b0, b1, b2, u, lb, Wtf,
                                          (float*)d_out);
}

// Round 7
// 180.319 us; speedup vs baseline: 1.1992x; 1.0089x over previous
//
#include <hip/hip_runtime.h>
#include <hip/hip_bf16.h>

typedef __attribute__((ext_vector_type(8))) short short8;
typedef __attribute__((ext_vector_type(4))) float floatx4;
typedef unsigned short ushort_t;
typedef unsigned int uint_t;

#define DOUT   256
#define KPAD   864          // 320 + 320 + 224 (segments padded to x32)
#define XPITCH 872          // ushorts per LDS row (436 dwords; 218 uint2)
#define TB     32           // tokens per block (verified structure)
#define NTOK   16384        // 32*512
#define NPREP_T 27          // fragment-transpose blocks (864/32 k-slabs)

static __device__ inline uint_t pack2bf(float x, float y) {
    __hip_bfloat162 h = __float22bfloat162_rn(make_float2(x, y));
    return *(uint_t*)&h;
}
static __device__ inline ushort_t f2bf(float f) {
    union { float f; uint_t u; } a; a.f = f;
    uint_t u = a.u;
    return (ushort_t)((u + 0x7FFFu + ((u >> 16) & 1u)) >> 16);
}
static __device__ inline float dot4(float4 a, float4 b) {
    return a.x * b.x + a.y * b.y + a.z * b.z + a.w * b.w;
}
// Non-temporal float4 load (nt flag: no-allocate/evict-first). Embedding rows
// have ~zero reuse within a dispatch — L1 allocation only throttles the gather.
// [verified +12.5 µs win in round 6]
static __device__ inline float4 ldnt(const float4* p) {
    floatx4 v = __builtin_nontemporal_load((const floatx4*)p);
    return make_float4(v.x, v.y, v.z, v.w);
}

// ---------------------------------------------------------------------------
// Merged prep (28 blocks) — VERIFIED PASSING in round 3. Unchanged.
// ---------------------------------------------------------------------------
__global__ __launch_bounds__(256) void k_prep(
    const float* __restrict__ W0, const float* __restrict__ W1,
    const float* __restrict__ W2,
    const float* __restrict__ b0, const float* __restrict__ b1,
    const float* __restrict__ b2,
    const float* __restrict__ Wa, const float* __restrict__ ba,
    float* __restrict__ u, float* __restrict__ lb, ushort_t* __restrict__ Wtf)
{
    __shared__ ushort_t tile[32][258];   // k-row x n-col, +2 pad
    int tid = threadIdx.x;
    int lane = tid & 63;
    int w = tid >> 6;                    // wave 0..3
    if (blockIdx.x < NPREP_T) {
        int kc = blockIdx.x;
        float4 wa4 = ((const float4*)Wa)[lane];     // cols 4*lane..4*lane+3
        float part[8];
        #pragma unroll
        for (int j = 0; j < 8; ++j) {
            int kk = w + 4 * j;                     // row within slab
            int kp = kc * 32 + kk;
            float4 v = make_float4(0.f, 0.f, 0.f, 0.f);
            const float* src = nullptr;
            if (kp < 320)      { if (kp < 300) src = W0 + kp * DOUT; }
            else if (kp < 640) { int o = kp - 320; if (o < 300) src = W1 + o * DOUT; }
            else               { int o = kp - 640; if (o < 200) src = W2 + o * DOUT; }
            if (src) v = *(const float4*)(src + 4 * lane);
            tile[kk][4 * lane + 0] = f2bf(v.x);
            tile[kk][4 * lane + 1] = f2bf(v.y);
            tile[kk][4 * lane + 2] = f2bf(v.z);
            tile[kk][4 * lane + 3] = f2bf(v.w);
            part[j] = dot4(v, wa4);
        }
        // u[k] = full-wave reduction of fp32 partials (each row lives in one wave)
        #pragma unroll
        for (int j = 0; j < 8; ++j) {
            float p = part[j];
            #pragma unroll
            for (int m = 1; m < 64; m <<= 1) p += __shfl_xor(p, m);
            if (lane == 0) u[kc * 32 + w + 4 * j] = p;
        }
        __syncthreads();
        int kq = (lane >> 4) * 8;
        int nc = lane & 15;
        #pragma unroll
        for (int i = 0; i < 4; ++i) {
            int nt = w * 4 + i;
            union { uint4 v; ushort_t s[8]; } pk;
            #pragma unroll
            for (int j = 0; j < 8; ++j) pk.s[j] = tile[kq + j][nt * 16 + nc];
            *(uint4*)(Wtf + ((size_t)(nt * 27 + kc) * 64 + lane) * 8) = pk.v;
        }
    } else {
        // tail: lb via waves 0..2; zero the u pad read by seg2 logit loads
        if (w < 3) {
            const float* bn = (w == 0) ? b0 : ((w == 1) ? b1 : b2);
            float acc = 0.f;
            #pragma unroll
            for (int j = 0; j < 4; ++j) {
                int c = lane + 64 * j;
                acc += bn[c] * Wa[c];
            }
            #pragma unroll
            for (int m = 1; m < 64; m <<= 1) acc += __shfl_xor(acc, m);
            if (lane == 0) lb[w] = acc + ba[0];
        }
        if (tid < 32) u[864 + tid] = 0.f;
    }
}

// ---------------------------------------------------------------------------
// Main: batched gather -> logits/softmax -> alpha-scaled bf16 pack -> single-acc
//       MFMA GEMM with fragment-streamed B -> epilogue (+ alpha-weighted bias).
// Block: 512 threads (8 waves), 32 tokens; grid 512.
// Round-6 kernel + ONE change: non-temporal stores in the epilogue (out is
// written once, never re-read -> stop polluting L1/L2 lines that the gather
// and Wtf streams need).
// ---------------------------------------------------------------------------
__global__ __launch_bounds__(512, 4) void k_main(
    const int* __restrict__ ids,
    const float* __restrict__ E0, const float* __restrict__ E1,
    const float* __restrict__ E2,
    const float* __restrict__ b0, const float* __restrict__ b1,
    const float* __restrict__ b2,
    const float* __restrict__ u, const float* __restrict__ lb,
    const ushort_t* __restrict__ Wtf,
    float* __restrict__ out)
{
    __shared__ __align__(16) ushort_t Xs[TB][XPITCH];   // 55808 B (alpha-scaled bf16)
    __shared__ float alphaS[TB][4];

    int tid = threadIdx.x;
    int tok0 = blockIdx.x * TB;

    // ---- batched gather: 16 threads/token; all 14 float4 loads pinned first ----
    int trow = tid >> 4, sub = tid & 15;
    int id = ids[tok0 + trow];
    uint2* Xd2 = (uint2*)&Xs[trow][0];
    const float4* p0 = (const float4*)E0 + (size_t)id * 75;
    const float4* p1 = (const float4*)E1 + (size_t)id * 75;
    const float4* p2 = (const float4*)E2 + (size_t)id * 50;
    float4 f4z = make_float4(0.f, 0.f, 0.f, 0.f);

    float4 g[14];
    g[0] = ldnt(p0 + sub);      g[1] = ldnt(p0 + sub + 16);
    g[2] = ldnt(p0 + sub + 32); g[3] = ldnt(p0 + sub + 48);
    g[4] = (sub < 11) ? ldnt(p0 + sub + 64) : f4z;
    g[5] = ldnt(p1 + sub);      g[6] = ldnt(p1 + sub + 16);
    g[7] = ldnt(p1 + sub + 32); g[8] = ldnt(p1 + sub + 48);
    g[9] = (sub < 11) ? ldnt(p1 + sub + 64) : f4z;
    g[10] = ldnt(p2 + sub);      g[11] = ldnt(p2 + sub + 16);
    g[12] = ldnt(p2 + sub + 32);
    g[13] = (sub < 2) ? ldnt(p2 + sub + 48) : f4z;
    __builtin_amdgcn_sched_barrier(0);   // keep all 14 loads issued before consume

    // ---- fp32 logit partials ----
    float l0 = 0.f, l1 = 0.f, l2 = 0.f;
    #pragma unroll
    for (int j = 0; j < 5; ++j) {
        float4 t = g[j], uu = *(const float4*)(u + 4 * (sub + 16 * j));
        l0 += t.x * uu.x + t.y * uu.y + t.z * uu.z + t.w * uu.w;
    }
    #pragma unroll
    for (int j = 0; j < 5; ++j) {
        float4 t = g[5 + j], uu = *(const float4*)(u + 320 + 4 * (sub + 16 * j));
        l1 += t.x * uu.x + t.y * uu.y + t.z * uu.z + t.w * uu.w;
    }
    #pragma unroll
    for (int j = 0; j < 4; ++j) {
        float4 t = g[10 + j], uu = *(const float4*)(u + 640 + 4 * (sub + 16 * j));
        l2 += t.x * uu.x + t.y * uu.y + t.z * uu.z + t.w * uu.w;
    }
    // butterfly over the token's 16 lanes -> every lane has the full sums
    #pragma unroll
    for (int m = 1; m < 16; m <<= 1) {
        l0 += __shfl_xor(l0, m);
        l1 += __shfl_xor(l1, m);
        l2 += __shfl_xor(l2, m);
    }
    l0 += lb[0]; l1 += lb[1]; l2 += lb[2];
    float mx = fmaxf(l0, fmaxf(l1, l2));
    float e0 = __expf(l0 - mx), e1 = __expf(l1 - mx), e2 = __expf(l2 - mx);
    float inv = 1.f / (e0 + e1 + e2);
    float a0 = e0 * inv, a1 = e1 * inv, a2 = e2 * inv;
    if (sub == 0) { alphaS[trow][0] = a0; alphaS[trow][1] = a1; alphaS[trow][2] = a2; }

    // ---- pack alpha-scaled bf16 into LDS (all writes within row pitch 218) ----
    #pragma unroll
    for (int j = 0; j < 5; ++j) {
        float4 t = g[j];
        Xd2[sub + 16 * j] = make_uint2(pack2bf(a0 * t.x, a0 * t.y), pack2bf(a0 * t.z, a0 * t.w));
    }
    #pragma unroll
    for (int j = 0; j < 5; ++j) {
        float4 t = g[5 + j];
        Xd2[80 + sub + 16 * j] = make_uint2(pack2bf(a1 * t.x, a1 * t.y), pack2bf(a1 * t.z, a1 * t.w));
    }
    #pragma unroll
    for (int j = 0; j < 3; ++j) {
        float4 t = g[10 + j];
        Xd2[160 + sub + 16 * j] = make_uint2(pack2bf(a2 * t.x, a2 * t.y), pack2bf(a2 * t.z, a2 * t.w));
    }
    if (sub < 2) {   // seg2 tail: only granules 48,49 are real data
        float4 t = g[13];
        Xd2[160 + 48 + sub] = make_uint2(pack2bf(a2 * t.x, a2 * t.y), pack2bf(a2 * t.z, a2 * t.w));
    }
    uint2 z2 = make_uint2(0u, 0u);
    for (int i = 75 + sub;  i < 80;  i += 16) Xd2[i] = z2;   // seg0 pad
    for (int i = 155 + sub; i < 160; i += 16) Xd2[i] = z2;   // seg1 pad
    for (int i = 210 + sub; i < 218; i += 16) Xd2[i] = z2;   // seg2 pad + row pad
    __syncthreads();

    // ---- MFMA GEMM: wave w owns N-tiles {2w, 2w+1}; single acc set ----
    int lane = tid & 63;
    int w = tid >> 6;               // 0..7
    int mrow = lane & 15;
    int kg8 = (lane >> 4) * 8;

    const ushort_t* bq0 = Wtf + ((size_t)((2 * w + 0) * 27) * 64 + lane) * 8;
    const ushort_t* bq1 = Wtf + ((size_t)((2 * w + 1) * 27) * 64 + lane) * 8;

    floatx4 acc[2][2];
    {
        floatx4 z = {0.f, 0.f, 0.f, 0.f};
        acc[0][0] = z; acc[0][1] = z; acc[1][0] = z; acc[1][1] = z;
    }

    #pragma unroll
    for (int kc = 0; kc < 27; ++kc) {
        short8 av0 = *(const short8*)&Xs[mrow][kc * 32 + kg8];
        short8 av1 = *(const short8*)&Xs[16 + mrow][kc * 32 + kg8];
        short8 bv0 = *(const short8*)(bq0 + kc * 512);
        short8 bv1 = *(const short8*)(bq1 + kc * 512);
        acc[0][0] = __builtin_amdgcn_mfma_f32_16x16x32_bf16(av0, bv0, acc[0][0], 0, 0, 0);
        acc[1][0] = __builtin_amdgcn_mfma_f32_16x16x32_bf16(av1, bv0, acc[1][0], 0, 0, 0);
        acc[0][1] = __builtin_amdgcn_mfma_f32_16x16x32_bf16(av0, bv1, acc[0][1], 0, 0, 0);
        acc[1][1] = __builtin_amdgcn_mfma_f32_16x16x32_bf16(av1, bv1, acc[1][1], 0, 0, 0);
    }

    // ---- epilogue: out = acc + a0*b0 + a1*b1 + a2*b2 (fp32), NT stores ----
    float bb0[2], bb1[2], bb2[2];
    #pragma unroll
    for (int nt = 0; nt < 2; ++nt) {
        int n = (2 * w + nt) * 16 + mrow;
        bb0[nt] = b0[n]; bb1[nt] = b1[n]; bb2[nt] = b2[n];
    }
    #pragma unroll
    for (int mt = 0; mt < 2; ++mt) {
        #pragma unroll
        for (int r = 0; r < 4; ++r) {
            int tok = mt * 16 + (lane >> 4) * 4 + r;
            float t0 = alphaS[tok][0], t1 = alphaS[tok][1], t2 = alphaS[tok][2];
            size_t rowoff = (size_t)(tok0 + tok) * DOUT;
            #pragma unroll
            for (int nt = 0; nt < 2; ++nt) {
                int n = (2 * w + nt) * 16 + mrow;
                float v = acc[mt][nt][r] + t0 * bb0[nt] + t1 * bb1[nt] + t2 * bb2[nt];
                __builtin_nontemporal_store(v, &out[rowoff + n]);
            }
        }
    }
}

extern "C" void kernel_launch(void* const* d_in, const int* in_sizes, int n_in,
                              void* d_out, int out_size, void* d_ws, size_t ws_size,
                              hipStream_t stream) {
    const int*   ids = (const int*)d_in[0];
    const float* E0  = (const float*)d_in[1];
    const float* E1  = (const float*)d_in[2];
    const float* E2  = (const float*)d_in[3];
    const float* W0  = (const float*)d_in[4];
    const float* b0  = (const float*)d_in[5];
    const float* W1  = (const float*)d_in[6];
    const float* b1  = (const float*)d_in[7];
    const float* W2  = (const float*)d_in[8];
    const float* b2  = (const float*)d_in[9];
    const float* Wa  = (const float*)d_in[10];
    const float* ba  = (const float*)d_in[11];

    float* u      = (float*)d_ws;                       // 896 floats (zero-padded)
    float* lb     = u + 896;                            // 3 floats
    ushort_t* Wtf = (ushort_t*)((char*)d_ws + 4096);    // 432 KB fragment-ordered B

    k_prep<<<NPREP_T + 1, 256, 0, stream>>>(W0, W1, W2, b0, b1, b2, Wa, ba,
                                            u, lb, Wtf);
    k_main<<<NTOK / TB, 512, 0, stream>>>(ids, E0, E1, E2, b0, b1, b2, u, lb, Wtf,
                                          (float*)d_out);
}